// Round 8
// baseline (923.790 us; speedup 1.0000x reference)
//
#include <hip/hip_runtime.h>

typedef unsigned short u16;
typedef unsigned int   u32;

#define DEV static __device__ __forceinline__

constexpr int S    = 2048;
constexpr int D    = 1024;
constexpr int H    = 16;
constexpr int BB   = 8;
constexpr int BH   = BB * H;        // 128
constexpr int BS   = BB * S;        // 16384 (b,s) rows
constexpr long NR  = (long)BH * S;  // 262144 (bh,s) rows

typedef __attribute__((ext_vector_type(8))) short bf16x8;
typedef __attribute__((ext_vector_type(4))) float f32x4;

DEV float b2f(u16 u) { return __uint_as_float(((u32)u) << 16); }
DEV u16   f2b(float f) {
  u32 x = __float_as_uint(f);
  u32 r = (x + 0x7fffu + ((x >> 16) & 1u)) >> 16;
  return (u16)r;
}
DEV float geluf(float x) { return 0.5f * x * (1.0f + erff(x * 0.70710678118654752440f)); }
DEV float sigmoidf(float z) { return 1.0f / (1.0f + expf(-z)); }
DEV float wsum(float v) {
#pragma unroll
  for (int o = 32; o > 0; o >>= 1) v += __shfl_xor(v, o, 64);
  return v;
}
DEV float rsum16(float v) {
  v += __shfl_xor(v, 1, 64);
  v += __shfl_xor(v, 2, 64);
  v += __shfl_xor(v, 4, 64);
  v += __shfl_xor(v, 8, 64);
  return v;
}
DEV float nan0(float v) {
  u32 b = __float_as_uint(v);
  return ((b & 0x7f800000u) == 0x7f800000u) ? 0.f : v;
}
DEV bool finitef(float v) {
  u32 b = __float_as_uint(v);
  return (b & 0x7f800000u) != 0x7f800000u;
}
DEV void dma16(const void* g, void* l) {
  __builtin_amdgcn_global_load_lds((const __attribute__((address_space(1))) void*)g,
                                   (__attribute__((address_space(3))) void*)l, 16, 0, 0);
}
DEV int swz4(int r) { return (r ^ (r >> 2)) & 3; }

// ---- x-normalize: (optionally compute rinv) and emit bf16 x*rinv*cw ----
template <bool FIRST>
__global__ void k_xnorm(const float* __restrict__ x, const float* __restrict__ cw,
                        float* __restrict__ rinv, u16* __restrict__ xb) {
  int row  = blockIdx.x * 4 + (threadIdx.x >> 6);
  int lane = threadIdx.x & 63;
  const float* p = x + (size_t)row * D;
  float4 v[4];
#pragma unroll
  for (int j = 0; j < 4; j++) v[j] = *(const float4*)(p + lane * 4 + j * 256);
  float rs;
  if (FIRST) {
    float s = 0.f;
#pragma unroll
    for (int j = 0; j < 4; j++)
      s += v[j].x * v[j].x + v[j].y * v[j].y + v[j].z * v[j].z + v[j].w * v[j].w;
    s = wsum(s);
    rs = rsqrtf(s * (1.0f / D) + 1e-6f);
    if (lane == 0) rinv[row] = rs;
  } else {
    rs = rinv[row];
  }
#pragma unroll
  for (int j = 0; j < 4; j++) {
    float4 w4 = *(const float4*)(cw + lane * 4 + j * 256);
    ushort4 o;
    o.x = f2b(v[j].x * rs * w4.x);
    o.y = f2b(v[j].y * rs * w4.y);
    o.z = f2b(v[j].z * rs * w4.z);
    o.w = f2b(v[j].w * rs * w4.w);
    *(ushort4*)&xb[(size_t)row * D + lane * 4 + j * 256] = o;
  }
}

// ---- transpose+convert the three projection weights -> WT[n][k] bf16 ----
__global__ void k_wtrans(const float* __restrict__ W0, const float* __restrict__ W1,
                         const float* __restrict__ W2, u16* __restrict__ WT) {
  __shared__ float tl[64][65];
  const float* W = blockIdx.z == 0 ? W0 : blockIdx.z == 1 ? W1 : W2;
  u16* dst = WT + (size_t)blockIdx.z * D * D;
  int bx = blockIdx.x, by = blockIdx.y;
  int t = threadIdx.x;
  int r = t >> 6, c = t & 63;
#pragma unroll
  for (int i = 0; i < 64; i += 4)
    tl[i + r][c] = W[(size_t)(bx * 64 + i + r) * D + by * 64 + c];
  __syncthreads();
#pragma unroll
  for (int i = 0; i < 64; i += 4)
    dst[(size_t)(by * 64 + i + r) * D + bx * 64 + c] = f2b(tl[c][i + r]);
}

// ---- pack [aw|tw] -> atw[n=32][k=1024] bf16 ----
__global__ void k_atw(const float* __restrict__ aw, const float* __restrict__ tw,
                      u16* __restrict__ atw) {
  int idx = blockIdx.x * 256 + threadIdx.x;  // 32768
  int n = idx >> 10, k = idx & 1023;
  float v = (n < 16) ? aw[(size_t)k * 16 + n] : tw[(size_t)k * 16 + (n - 16)];
  atw[idx] = f2b(v);
}

// ---- MFMA projection GEMM: xb(16384x1024 bf16) @ W (via WT[n][k] bf16) ----
template <bool NORM>
__global__ __launch_bounds__(256) void k_proj_mfma(
    const u16* __restrict__ xb, const u16* __restrict__ WT,
    const float* __restrict__ hw, u16* __restrict__ outp) {
  __shared__ u16 As[128 * 32];
  __shared__ u16 Bs[128 * 32];
  int t = threadIdx.x;
  int wave = t >> 6, lane = t & 63;
  int wm = wave >> 1, wn = wave & 1;
  int m0 = blockIdx.y * 128, n0 = blockIdx.x * 128;
  int quad = lane >> 4, l15 = lane & 15;
  int rl = lane >> 2;
  int q  = (lane & 3) ^ swz4(rl);

  f32x4 acc[4][4] = {};

  int aoff[4], boff[4];
#pragma unroll
  for (int f = 0; f < 4; f++) {
    aoff[f] = (wm * 64 + f * 16 + l15) * 32 + (quad ^ swz4(l15)) * 8;
    boff[f] = (wn * 64 + f * 16 + l15) * 32 + (quad ^ swz4(l15)) * 8;
  }
  const u16* ga0 = xb + (size_t)(m0 + wave * 32 + rl) * D + q * 8;
  const u16* ga1 = ga0 + 16 * D;
  const u16* gb0 = WT + (size_t)(n0 + wave * 32 + rl) * D + q * 8;
  const u16* gb1 = gb0 + 16 * D;
  u16* lA0 = &As[(wave * 32) * 32];
  u16* lA1 = &As[(wave * 32 + 16) * 32];
  u16* lB0 = &Bs[(wave * 32) * 32];
  u16* lB1 = &Bs[(wave * 32 + 16) * 32];

  for (int k0 = 0; k0 < D; k0 += 32) {
    dma16(ga0 + k0, lA0);
    dma16(ga1 + k0, lA1);
    dma16(gb0 + k0, lB0);
    dma16(gb1 + k0, lB1);
    __syncthreads();
    bf16x8 af[4], bfr[4];
#pragma unroll
    for (int f = 0; f < 4; f++) {
      af[f]  = *(const bf16x8*)&As[aoff[f]];
      bfr[f] = *(const bf16x8*)&Bs[boff[f]];
    }
#pragma unroll
    for (int i = 0; i < 4; i++)
#pragma unroll
      for (int j = 0; j < 4; j++)
        acc[i][j] = __builtin_amdgcn_mfma_f32_16x16x32_bf16(af[i], bfr[j], acc[i][j], 0, 0, 0);
    __syncthreads();
  }

  int h = blockIdx.x * 2 + wn;
  float hwv[4];
  if (NORM) {
#pragma unroll
    for (int f = 0; f < 4; f++) hwv[f] = hw[f * 16 + l15];
  }
#pragma unroll
  for (int fm = 0; fm < 4; fm++) {
    f32x4 rn = {};
    if (NORM) {
      f32x4 ss = acc[fm][0] * acc[fm][0] + acc[fm][1] * acc[fm][1] +
                 acc[fm][2] * acc[fm][2] + acc[fm][3] * acc[fm][3];
#pragma unroll
      for (int c = 0; c < 4; c++) {
        float s = rsum16(ss[c]);
        rn[c] = rsqrtf(s * (1.f / 64) + 1e-6f);
      }
    }
#pragma unroll
    for (int r = 0; r < 4; r++) {
      int gr = m0 + wm * 64 + fm * 16 + quad * 4 + r;
      int b = gr >> 11, s_ = gr & 2047;
      size_t base = ((size_t)(b * 16 + h) * S + s_) * 64 + l15;
#pragma unroll
      for (int fn = 0; fn < 4; fn++) {
        float v = acc[fm][fn][r];
        if (NORM) v *= rn[r] * hwv[fn];
        outp[base + fn * 16] = f2b(v);
      }
    }
  }
}

// ---- alpha/theta via MFMA: sigmoid(xs @ atw^T + bias), theta *= MAX_LR ----
__global__ __launch_bounds__(256) void k_ate2(
    const u16* __restrict__ xb, const u16* __restrict__ atw,
    const float* __restrict__ ab, const float* __restrict__ tb,
    float* __restrict__ alpha, float* __restrict__ theta) {
  __shared__ u16 As[2][128 * 32];
  __shared__ u16 Bs[2][32 * 32];
  int t = threadIdx.x;
  int wave = t >> 6, lane = t & 63;
  int m0 = blockIdx.x * 128;
  int quad = lane >> 4, l15 = lane & 15;
  int rl = lane >> 2;
  int q = (lane & 3) ^ swz4(rl);

  f32x4 acc[2][2] = {};
  int aoff[2], boff[2];
#pragma unroll
  for (int f = 0; f < 2; f++) {
    aoff[f] = (wave * 32 + f * 16 + l15) * 32 + (quad ^ swz4(l15)) * 8;
    boff[f] = (f * 16 + l15) * 32 + (quad ^ swz4(l15)) * 8;
  }
  const u16* ga0 = xb + (size_t)(m0 + wave * 32 + rl) * D + q * 8;
  const u16* ga1 = ga0 + 16 * D;
  const u16* gb = atw + (size_t)((wave & 1) * 16 + rl) * D + (wave >> 1) * 32 + q * 8;
  u16* lA0h0 = &As[0][(wave * 32) * 32];
  u16* lA1h0 = &As[0][(wave * 32 + 16) * 32];
  u16* lA0h1 = &As[1][(wave * 32) * 32];
  u16* lA1h1 = &As[1][(wave * 32 + 16) * 32];
  u16* lB    = &Bs[wave >> 1][((wave & 1) * 16) * 32];

  for (int k0 = 0; k0 < D; k0 += 64) {
    dma16(ga0 + k0, lA0h0);
    dma16(ga1 + k0, lA1h0);
    dma16(ga0 + k0 + 32, lA0h1);
    dma16(ga1 + k0 + 32, lA1h1);
    dma16(gb + k0, lB);
    __syncthreads();
#pragma unroll
    for (int h = 0; h < 2; h++) {
      bf16x8 af[2], bfr[2];
#pragma unroll
      for (int f = 0; f < 2; f++) {
        af[f]  = *(const bf16x8*)&As[h][aoff[f]];
        bfr[f] = *(const bf16x8*)&Bs[h][boff[f]];
      }
#pragma unroll
      for (int i = 0; i < 2; i++)
#pragma unroll
        for (int j = 0; j < 2; j++)
          acc[i][j] = __builtin_amdgcn_mfma_f32_16x16x32_bf16(af[i], bfr[j], acc[i][j], 0, 0, 0);
    }
    __syncthreads();
  }

#pragma unroll
  for (int fn = 0; fn < 2; fn++) {
    float bias = (fn == 0) ? ab[l15] : tb[l15];
    float scale = (fn == 0) ? 1.f : 0.01f;  // MAX_LR
    float* dst = (fn == 0) ? alpha : theta;
#pragma unroll
    for (int fm = 0; fm < 2; fm++) {
#pragma unroll
      for (int r = 0; r < 4; r++) {
        int gr = m0 + wave * 32 + fm * 16 + quad * 4 + r;
        int b = gr >> 11, s_ = gr & 2047;
        float v = sigmoidf(acc[fm][fn][r] + bias) * scale;
        dst[(long)(b * 16 + l15) * S + s_] = v;
      }
    }
  }
}

// ---------------- per-bh mean of alpha ----------------
__global__ void k_mean(const float* __restrict__ alpha, float* __restrict__ amean) {
  int bh = blockIdx.x, t = threadIdx.x;
  float sa = 0.f;
  for (int i = t; i < S; i += 256) sa += alpha[(long)bh * S + i];
  sa = wsum(sa);
  __shared__ float sh[4];
  int w = t >> 6, lane = t & 63;
  if (lane == 0) sh[w] = sa;
  __syncthreads();
  if (t == 0) amean[bh] = (sh[0] + sh[1] + sh[2] + sh[3]) * (1.f / S);
}

// ---- small-weight prep: W0T[i][k], W1b[i][o] (direct), W1T[o][i] bf16 ----
__global__ void k_wsmall(const float* __restrict__ W0, const float* __restrict__ W1,
                         u16* __restrict__ W0T, u16* __restrict__ W1b, u16* __restrict__ W1T) {
  int idx = blockIdx.x * 256 + threadIdx.x;  // 16384
  int sec = blockIdx.y;
  if (sec == 0) {
    int k = idx & 63, i = idx >> 6;
    W0T[idx] = f2b(W0[k * 256 + i]);
  } else if (sec == 1) {
    W1b[idx] = f2b(W1[idx]);
  } else {
    int i = idx & 255, o = idx >> 8;
    W1T[idx] = f2b(W1[i * 64 + o]);
  }
}

// ---- rows (row-major [s][64]) -> blocked-T tiles (all NR rows) ----
__global__ void k_keysT(const u16* __restrict__ keysg, u16* __restrict__ blk) {
  long idx = (long)blockIdx.x * 256 + threadIdx.x;  // NR*16
  int col = (int)(idx & 63);
  long s = (idx >> 6) * 4;
  ushort4 o;
  o.x = keysg[(size_t)s * 64 + col];
  o.y = keysg[(size_t)(s + 1) * 64 + col];
  o.z = keysg[(size_t)(s + 2) * 64 + col];
  o.w = keysg[(size_t)(s + 3) * 64 + col];
  *(ushort4*)&blk[((size_t)(s >> 4) * 4 + (col >> 4)) * 256 + (col & 15) * 16 + (s & 15)] = o;
}

// ==================== fused memory-grad kernel (80 KB LDS, 2 blocks/CU) ====
// One block = 128 rows of one bh. PRE -> gelu/gelu' -> h1 -> rmsnorm-bwd ->
// dh -> g1 (atomic) -> dh0 -> g0 (atomic). MFMA A/B fragments whose global
// layout already matches fragment shape are read DIRECT from global (W0T,
// W1T, W1b L1/L2-resident; keys row-major for ph2-A; keysTb blocked for
// ph6-A) — no LDS staging. LDS: S1(64K) act->dh0 blocked | dhblk(16K).
__global__ __launch_bounds__(512, 2) void kfuse(
    const u16* __restrict__ keysv, const u16* __restrict__ vals,
    const u16* __restrict__ keysTb,
    const u16* __restrict__ W0T, const u16* __restrict__ W1T,
    const u16* __restrict__ W1b, const float* __restrict__ theta,
    float* __restrict__ g0t, float* __restrict__ g1t) {
  __shared__ u16 L[40960];
  u16* S1    = L;           // 32768 u16 (64 KB)
  u16* dhblk = L + 32768;   // 8192 u16 (16 KB)

  int t = threadIdx.x;
  int w = t >> 6, lane = t & 63;
  int quad = lane >> 4, l15 = lane & 15;
  int bh = blockIdx.y, strip = blockIdx.x;
  long grow = (long)bh * S + strip * 128;  // global row base

  // ---- ph2: PRE = keys @ W0  (M=16/wave, N=256, K=64) ----
  f32x4 acc2[4];   // reused for h1 later
  ushort4 gpr[16]; // gelu' in registers
  {
    f32x4 acc[16] = {};
    const u16* krow = keysv + (grow + w * 16 + l15) * 64 + quad * 8;
    bf16x8 afA0 = *(const bf16x8*)(krow);
    bf16x8 afA1 = *(const bf16x8*)(krow + 32);
#pragma unroll
    for (int f = 0; f < 16; f++) {
      bf16x8 b0 = *(const bf16x8*)&W0T[(f * 16 + l15) * 64 + quad * 8];
      bf16x8 b1 = *(const bf16x8*)&W0T[(f * 16 + l15) * 64 + 32 + quad * 8];
      acc[f] = __builtin_amdgcn_mfma_f32_16x16x32_bf16(afA0, b0, acc[f], 0, 0, 0);
      acc[f] = __builtin_amdgcn_mfma_f32_16x16x32_bf16(afA1, b1, acc[f], 0, 0, 0);
    }
    // epi: act -> S1 blocked (own rows), gelu' -> registers
#pragma unroll
    for (int f = 0; f < 16; f++) {
      ushort4 oa, og;
#pragma unroll
      for (int r = 0; r < 4; r++) {
        float v = acc[f][r];
        float cdf = 0.5f * (1.0f + erff(v * 0.70710678118654752440f));
        float pdf = expf(-0.5f * v * v) * 0.3989422804014327f;
        ((u16*)&oa)[r] = f2b(v * cdf);
        ((u16*)&og)[r] = f2b(cdf + v * pdf);
      }
      *(ushort4*)&S1[(w * 16 + f) * 256 + l15 * 16 + quad * 4] = oa;
      gpr[f] = og;
    }
  }

  // ---- ph3: h1 = act @ W1 (M=16/wave, N=64, K=256); own-wave S1 rows ----
  {
#pragma unroll
    for (int fn = 0; fn < 4; fn++) acc2[fn] = (f32x4){};
#pragma unroll
    for (int kc = 0; kc < 8; kc++) {
      union { bf16x8 v; u16 e[8]; } u;
#pragma unroll
      for (int j = 0; j < 8; j++) {
        int c = kc * 32 + quad * 8 + j;
        u.e[j] = S1[(w * 16 + (c >> 4)) * 256 + (c & 15) * 16 + l15];
      }
#pragma unroll
      for (int fn = 0; fn < 4; fn++) {
        bf16x8 bv = *(const bf16x8*)&W1T[(size_t)(fn * 16 + l15) * 256 + kc * 32 + quad * 8];
        acc2[fn] = __builtin_amdgcn_mfma_f32_16x16x32_bf16(u.v, bv, acc2[fn], 0, 0, 0);
      }
    }
  }

  // ---- ph3-epi: pf-rmsnorm bwd -> dh (dhblk blocked, own rows) ----
  {
    f32x4 ss = acc2[0] * acc2[0] + acc2[1] * acc2[1] +
               acc2[2] * acc2[2] + acc2[3] * acc2[3];
    f32x4 rrms, th2;
    long rowg0 = grow + w * 16 + quad * 4;
#pragma unroll
    for (int r = 0; r < 4; r++) {
      float s = rsum16(ss[r]);
      rrms[r] = rsqrtf(s * (1.f / 64) + 1e-8f);
      th2[r] = 2.f * theta[rowg0 + r];
    }
    f32x4 hn[4], dp[4];
    f32x4 dyp = {};
#pragma unroll
    for (int fn = 0; fn < 4; fn++) {
      int col = fn * 16 + l15;
#pragma unroll
      for (int r = 0; r < 4; r++) {
        float h = acc2[fn][r] * rrms[r];
        float k = b2f(keysv[(rowg0 + r) * 64 + col]);
        float v = b2f(vals[(rowg0 + r) * 64 + col]);
        float d = th2[r] * (h + k - v);
        hn[fn][r] = h;
        dp[fn][r] = d;
        dyp[r] += d * h;
      }
    }
#pragma unroll
    for (int r = 0; r < 4; r++) dyp[r] = rsum16(dyp[r]);
#pragma unroll
    for (int fn = 0; fn < 4; fn++) {
      ushort4 ob;
#pragma unroll
      for (int r = 0; r < 4; r++) {
        float d = (dp[fn][r] - hn[fn][r] * dyp[r] * (1.f / 64)) * rrms[r];
        ((u16*)&ob)[r] = f2b(d);
      }
      *(ushort4*)&dhblk[(w * 4 + fn) * 256 + l15 * 16 + quad * 4] = ob;
    }
  }
  __syncthreads();  // dh + ACT fully visible

  // ---- ph4: g1[o][i] += dh^T @ act  (kg pattern, K=128 rows) ----
  {
    int qh = quad >> 1, ql = (quad & 1) * 8;
    f32x4 a3[4][2] = {};
#pragma unroll
    for (int ks = 0; ks < 4; ks++) {
      int s16 = ks * 2 + qh;
      bf16x8 af[4], bf2[2];
#pragma unroll
      for (int m = 0; m < 4; m++)
        af[m] = *(const bf16x8*)&dhblk[(s16 * 4 + m) * 256 + l15 * 16 + ql];
#pragma unroll
      for (int f2 = 0; f2 < 2; f2++)
        bf2[f2] = *(const bf16x8*)&S1[(s16 * 16 + w * 2 + f2) * 256 + l15 * 16 + ql];
#pragma unroll
      for (int m = 0; m < 4; m++)
#pragma unroll
        for (int f2 = 0; f2 < 2; f2++)
          a3[m][f2] = __builtin_amdgcn_mfma_f32_16x16x32_bf16(af[m], bf2[f2], a3[m][f2], 0, 0, 0);
    }
    float* gp1 = g1t + (size_t)bh * 16384;
#pragma unroll
    for (int m = 0; m < 4; m++)
#pragma unroll
      for (int f2 = 0; f2 < 2; f2++) {
        int n = w * 32 + f2 * 16 + l15;
#pragma unroll
        for (int r = 0; r < 4; r++)
          atomicAdd(&gp1[(size_t)(m * 16 + quad * 4 + r) * 256 + n], a3[m][f2][r]);
      }
  }
  __syncthreads();  // ACT dead; S1 reusable for dh0blk

  // ---- ph5: dh0 = (dh @ W1^T) .* gelu'  -> S1 blocked ----
  {
    f32x4 a5[16] = {};
    bf16x8 afd[2];
#pragma unroll
    for (int kc = 0; kc < 2; kc++) {
      union { bf16x8 v; u16 e[8]; } u;
#pragma unroll
      for (int j = 0; j < 8; j++) {
        int col = kc * 32 + quad * 8 + j;
        u.e[j] = dhblk[(w * 4 + (col >> 4)) * 256 + (col & 15) * 16 + l15];
      }
      afd[kc] = u.v;
    }
#pragma unroll
    for (int f = 0; f < 16; f++) {
#pragma unroll
      for (int kc = 0; kc < 2; kc++) {
        bf16x8 bv = *(const bf16x8*)&W1b[(size_t)(f * 16 + l15) * 64 + kc * 32 + quad * 8];
        a5[f] = __builtin_amdgcn_mfma_f32_16x16x32_bf16(afd[kc], bv, a5[f], 0, 0, 0);
      }
    }
#pragma unroll
    for (int f = 0; f < 16; f++) {
      ushort4 od;
#pragma unroll
      for (int r = 0; r < 4; r++)
        ((u16*)&od)[r] = f2b(a5[f][r] * b2f(((u16*)&gpr[f])[r]));
      *(ushort4*)&S1[(w * 16 + f) * 256 + l15 * 16 + quad * 4] = od;
    }
  }
  __syncthreads();

  // ---- ph6: g0[k][i] += keys^T @ dh0  (A from blocked keysTb global) ----
  {
    int qh = quad >> 1, ql = (quad & 1) * 8;
    const u16* Kg = keysTb + (size_t)(grow >> 4) * 1024;
    f32x4 a6[4][2] = {};
#pragma unroll
    for (int ks = 0; ks < 4; ks++) {
      int s16 = ks * 2 + qh;
      bf16x8 af[4], bf2[2];
#pragma unroll
      for (int m = 0; m < 4; m++)
        af[m] = *(const bf16x8*)&Kg[(size_t)(s16 * 4 + m) * 256 + l15 * 16 + ql];
#pragma unroll
      for (int f2 = 0; f2 < 2; f2++)
        bf2[f2] = *(const bf16x8*)&S1[(s16 * 16 + w * 2 + f2) * 256 + l15 * 16 + ql];
#pragma unroll
      for (int m = 0; m < 4; m++)
#pragma unroll
        for (int f2 = 0; f2 < 2; f2++)
          a6[m][f2] = __builtin_amdgcn_mfma_f32_16x16x32_bf16(af[m], bf2[f2], a6[m][f2], 0, 0, 0);
    }
    float* gp0 = g0t + (size_t)bh * 16384;
#pragma unroll
    for (int m = 0; m < 4; m++)
#pragma unroll
      for (int f2 = 0; f2 < 2; f2++) {
        int n = w * 32 + f2 * 16 + l15;
#pragma unroll
        for (int r = 0; r < 4; r++)
          atomicAdd(&gp0[(size_t)(m * 16 + quad * 4 + r) * 256 + n], a6[m][f2][r]);
      }
  }
}

// ==================== fused retrieve kernel (64 KB LDS, 2 blocks/CU) ====
// One block = 128 rows (one strip) of one bh. q(row-major) @ nW0 -> gelu ->
// act(LDS) @ nW1 -> nan0 + pf-rmsnorm + q-residual -> out. A/B fragments
// read direct from global; LDS = act only; zero barriers.
__global__ __launch_bounds__(512, 2) void kret(
    const u16* __restrict__ qp, const u16* __restrict__ nW0T,
    const u16* __restrict__ nW1T, float* __restrict__ outp) {
  __shared__ u16 S1[32768];  // 64 KB act blocked

  int t = threadIdx.x;
  int w = t >> 6, lane = t & 63;
  int quad = lane >> 4, l15 = lane & 15;
  int bh = blockIdx.y, strip = blockIdx.x;
  long grow = (long)bh * S + strip * 128;

  // ---- ph2: PRE = q @ nW0 (M=16/wave, N=256, K=64); act=gelu -> S1 ----
  {
    f32x4 acc[16] = {};
    const u16* qrow = qp + (grow + w * 16 + l15) * 64 + quad * 8;
    bf16x8 afA0 = *(const bf16x8*)(qrow);
    bf16x8 afA1 = *(const bf16x8*)(qrow + 32);
    const u16* W0p = nW0T + (size_t)bh * 16384;
#pragma unroll
    for (int f = 0; f < 16; f++) {
      bf16x8 b0 = *(const bf16x8*)&W0p[(f * 16 + l15) * 64 + quad * 8];
      bf16x8 b1 = *(const bf16x8*)&W0p[(f * 16 + l15) * 64 + 32 + quad * 8];
      acc[f] = __builtin_amdgcn_mfma_f32_16x16x32_bf16(afA0, b0, acc[f], 0, 0, 0);
      acc[f] = __builtin_amdgcn_mfma_f32_16x16x32_bf16(afA1, b1, acc[f], 0, 0, 0);
    }
#pragma unroll
    for (int f = 0; f < 16; f++) {
      ushort4 oa;
#pragma unroll
      for (int r = 0; r < 4; r++) ((u16*)&oa)[r] = f2b(geluf(acc[f][r]));
      *(ushort4*)&S1[(w * 16 + f) * 256 + l15 * 16 + quad * 4] = oa;
    }
  }
  // ph3 reads only own-wave S1 rows — no barrier.

  // ---- ph3: h1 = act @ nW1 (M=16/wave, N=64, K=256) ----
  f32x4 acc2[4];
#pragma unroll
  for (int fn = 0; fn < 4; fn++) acc2[fn] = (f32x4){};
  const u16* W1p = nW1T + (size_t)bh * 16384;
#pragma unroll
  for (int kc = 0; kc < 8; kc++) {
    union { bf16x8 v; u16 e[8]; } u;
#pragma unroll
    for (int j = 0; j < 8; j++) {
      int c = kc * 32 + quad * 8 + j;
      u.e[j] = S1[(w * 16 + (c >> 4)) * 256 + (c & 15) * 16 + l15];
    }
#pragma unroll
    for (int fn = 0; fn < 4; fn++) {
      bf16x8 bv = *(const bf16x8*)&W1p[(size_t)(fn * 16 + l15) * 256 + kc * 32 + quad * 8];
      acc2[fn] = __builtin_amdgcn_mfma_f32_16x16x32_bf16(u.v, bv, acc2[fn], 0, 0, 0);
    }
  }

  // ---- epilogue: nan0 + pf_rmsnorm + q residual -> out (merge heads) ----
  {
    f32x4 hv[4];
    f32x4 ss = {};
#pragma unroll
    for (int fn = 0; fn < 4; fn++) {
#pragma unroll
      for (int r = 0; r < 4; r++) {
        float v = nan0(acc2[fn][r]);
        hv[fn][r] = v;
        ss[r] += v * v;
      }
    }
    f32x4 rrms;
#pragma unroll
    for (int r = 0; r < 4; r++) {
      float s = rsum16(ss[r]);
      rrms[r] = rsqrtf(s * (1.f / 64) + 1e-8f);
    }
    long b = bh >> 4, hh = bh & 15;
#pragma unroll
    for (int r = 0; r < 4; r++) {
      long s_ = strip * 128 + w * 16 + quad * 4 + r;
      long gr = grow + w * 16 + quad * 4 + r;
      size_t obase = (size_t)(b * S + s_) * D + hh * 64;
#pragma unroll
      for (int fn = 0; fn < 4; fn++) {
        int col = fn * 16 + l15;
        outp[obase + col] = hv[fn][r] * rrms[r] + b2f(qp[gr * 64 + col]);
      }
    }
  }
}

// ---------------- zero-fill ----------------
__global__ void k_zero(float* __restrict__ p, long n) {
  long i = (long)blockIdx.x * 256 + threadIdx.x;
  if (i < n) p[i] = 0.f;
}

// ---------------- grad-norm clip coefficient per bh ----------------
__global__ void k_clip(const float* __restrict__ g0, const float* __restrict__ g1,
                       float* __restrict__ coef) {
  int bh = blockIdx.x, t = threadIdx.x;
  const float* p0 = g0 + (long)bh * 16384;
  const float* p1 = g1 + (long)bh * 16384;
  float s = 0.f;
  for (int i = t; i < 16384; i += 256) {
    float a = p0[i]; s += a * a;
    float b = p1[i]; s += b * b;
  }
  s = wsum(s);
  __shared__ float sh[4];
  int w = t >> 6, lane = t & 63;
  if (lane == 0) sh[w] = s;
  __syncthreads();
  if (t == 0) {
    float tot = sh[0] + sh[1] + sh[2] + sh[3];
    float c = 10.f / (sqrtf(tot) + 1e-6f);
    coef[bh] = fminf(c, 1.f);
  }
}

// ---- weight update -> transposed bf16 fast weights for retrieve MFMA ----
__global__ void k_updT(const float* __restrict__ W0, const float* __restrict__ W1,
                       const float* __restrict__ g0t, const float* __restrict__ g1t,
                       const float* __restrict__ amean, const float* __restrict__ coef,
                       u16* __restrict__ nW0T, u16* __restrict__ nW1T) {
  long i = (long)blockIdx.x * 256 + threadIdx.x;  // 2 * BH * 16384
  int half = (int)(i >> 21);
  long j = i & ((1L << 21) - 1);
  int bh = (int)(j >> 14);
  int idx = (int)(j & 16383);
  float a = 1.f - amean[bh], cf = coef[bh];
  if (half == 0) {
    int k = idx & 63, ii = idx >> 6;
    float w = W0[k * 256 + ii];
    float nw = a * w - cf * g0t[(long)bh * 16384 + k * 256 + ii];
    if (!finitef(nw)) nw = w;
    nW0T[j] = f2b(nw);
  } else {
    int ii = idx & 255, o = idx >> 8;
    float w = W1[ii * 64 + o];
    float nw = a * w - cf * g1t[(long)bh * 16384 + idx];
    if (!finitef(nw)) nw = w;
    nW1T[j] = f2b(nw);
  }
}

extern "C" void kernel_launch(void* const* d_in, const int* in_sizes, int n_in,
                              void* d_out, int out_size, void* d_ws, size_t ws_size,
                              hipStream_t stream) {
  const float* x   = (const float*)d_in[0];
  const float* W_K = (const float*)d_in[1];
  const float* W_V = (const float*)d_in[2];
  const float* W_Q = (const float*)d_in[3];
  const float* mW0 = (const float*)d_in[4];
  const float* mW1 = (const float*)d_in[5];
  const float* knw = (const float*)d_in[6];
  const float* qnw = (const float*)d_in[7];
  const float* snw = (const float*)d_in[8];
  const float* rnw = (const float*)d_in[9];
  const float* aw  = (const float*)d_in[10];
  const float* ab  = (const float*)d_in[11];
  const float* tw  = (const float*)d_in[12];
  const float* tb  = (const float*)d_in[13];
  float* out = (float*)d_out;
  (void)ws_size; (void)in_sizes; (void)n_in; (void)out_size;

  // workspace carve-up
  char* w = (char*)d_ws;
  auto alloc = [&](size_t bytes) {
    char* p = w;
    w += (bytes + 255) / 256 * 256;
    return p;
  };
  float* rinv   = (float*)alloc((size_t)BS * 4);
  u16*   xs     = (u16*)alloc((size_t)BS * D * 2);        // 32 MB
  u16*   WTb    = (u16*)alloc((size_t)3 * D * D * 2);     // 6 MB
  u16*   keys   = (u16*)alloc(NR * 64 * 2);               // 32 MB (reused as q)
  u16*   vals   = (u16*)alloc(NR * 64 * 2);               // 32 MB
  float* alpha  = (float*)alloc(NR * 4);                  // 1 MB
  float* theta  = (float*)alloc(NR * 4);                  // 1 MB
  float* amean  = (float*)alloc(BH * 4);
  float* coef   = (float*)alloc(BH * 4);
  u16*   W0T    = (u16*)alloc(16384 * 2);
  u16*   W1b    = (u16*)alloc(16384 * 2);
  u16*   W1T    = (u16*)alloc(16384 * 2);
  u16*   atw    = (u16*)alloc((size_t)32 * D * 2);        // 64 KB
  u16*   keysTb = (u16*)alloc(NR * 64 * 2);               // 32 MB (blocked)
  float* g0t    = (float*)alloc((size_t)BH * 16384 * 4);  // 8 MB
  float* g1t    = (float*)alloc((size_t)BH * 16384 * 4);  // 8 MB
  u16*   nW0T   = (u16*)alloc((size_t)BH * 16384 * 2);    // 4 MB
  u16*   nW1T   = (u16*)alloc((size_t)BH * 16384 * 2);    // 4 MB

  // ---- store path ----
  k_xnorm<true><<<BS / 4, 256, 0, stream>>>(x, snw, rinv, xs);
  k_wtrans<<<dim3(16, 16, 3), 256, 0, stream>>>(W_K, W_V, W_Q, WTb);
  k_atw<<<128, 256, 0, stream>>>(aw, tw, atw);
  k_proj_mfma<true><<<dim3(8, 128), 256, 0, stream>>>(xs, WTb, knw, keys);
  k_proj_mfma<false><<<dim3(8, 128), 256, 0, stream>>>(xs, WTb + (size_t)D * D, nullptr, vals);
  k_ate2<<<BS / 128, 256, 0, stream>>>(xs, atw, ab, tb, alpha, theta);
  k_mean<<<BH, 256, 0, stream>>>(alpha, amean);
  k_wsmall<<<dim3(64, 3), 256, 0, stream>>>(mW0, mW1, W0T, W1b, W1T);
  k_zero<<<(int)((2L * BH * 16384 + 255) / 256), 256, 0, stream>>>(g0t, 2L * BH * 16384);

  // ---- memory grad: blocked keys once, then one fused kernel ----
  k_keysT<<<(int)(NR / 16), 256, 0, stream>>>(keys, keysTb);
  kfuse<<<dim3(16, BH), 512, 0, stream>>>(keys, vals, keysTb, W0T, W1T, W1b,
                                          theta, g0t, g1t);

  k_clip<<<BH, 256, 0, stream>>>(g0t, g1t, coef);
  k_updT<<<(int)(2L * BH * 16384 / 256), 256, 0, stream>>>(
      mW0, mW1, g0t, g1t, amean, coef, nW0T, nW1T);

  // ---- retrieve: q proj, one fused kernel (q read row-major; no qTb) ----
  k_xnorm<false><<<BS / 4, 256, 0, stream>>>(x, rnw, rinv, xs);
  u16* q = keys;
  k_proj_mfma<true><<<dim3(8, 128), 256, 0, stream>>>(xs, WTb + (size_t)2 * D * D, qnw, q);
  kret<<<dim3(16, BH), 512, 0, stream>>>(q, nW0T, nW1T, out);
}

// Round 9
// 855.480 us; speedup vs baseline: 1.0799x; 1.0799x over previous
//
#include <hip/hip_runtime.h>

typedef unsigned short u16;
typedef unsigned int   u32;

#define DEV static __device__ __forceinline__

constexpr int S    = 2048;
constexpr int D    = 1024;
constexpr int H    = 16;
constexpr int BB   = 8;
constexpr int BH   = BB * H;        // 128
constexpr int BS   = BB * S;        // 16384 (b,s) rows
constexpr long NR  = (long)BH * S;  // 262144 (bh,s) rows

typedef __attribute__((ext_vector_type(8))) short bf16x8;
typedef __attribute__((ext_vector_type(4))) float f32x4;

DEV float b2f(u16 u) { return __uint_as_float(((u32)u) << 16); }
DEV u16   f2b(float f) {
  u32 x = __float_as_uint(f);
  u32 r = (x + 0x7fffu + ((x >> 16) & 1u)) >> 16;
  return (u16)r;
}
DEV float geluf(float x) { return 0.5f * x * (1.0f + erff(x * 0.70710678118654752440f)); }
DEV float sigmoidf(float z) { return 1.0f / (1.0f + expf(-z)); }
DEV float wsum(float v) {
#pragma unroll
  for (int o = 32; o > 0; o >>= 1) v += __shfl_xor(v, o, 64);
  return v;
}
DEV float rsum16(float v) {
  v += __shfl_xor(v, 1, 64);
  v += __shfl_xor(v, 2, 64);
  v += __shfl_xor(v, 4, 64);
  v += __shfl_xor(v, 8, 64);
  return v;
}
DEV float nan0(float v) {
  u32 b = __float_as_uint(v);
  return ((b & 0x7f800000u) == 0x7f800000u) ? 0.f : v;
}
DEV bool finitef(float v) {
  u32 b = __float_as_uint(v);
  return (b & 0x7f800000u) != 0x7f800000u;
}
DEV void dma16(const void* g, void* l) {
  __builtin_amdgcn_global_load_lds((const __attribute__((address_space(1))) void*)g,
                                   (__attribute__((address_space(3))) void*)l, 16, 0, 0);
}
DEV int swz4(int r) { return (r ^ (r >> 2)) & 3; }

// ---- x-normalize: (optionally compute rinv) and emit bf16 x*rinv*cw ----
template <bool FIRST>
__global__ void k_xnorm(const float* __restrict__ x, const float* __restrict__ cw,
                        float* __restrict__ rinv, u16* __restrict__ xb) {
  int row  = blockIdx.x * 4 + (threadIdx.x >> 6);
  int lane = threadIdx.x & 63;
  const float* p = x + (size_t)row * D;
  float4 v[4];
#pragma unroll
  for (int j = 0; j < 4; j++) v[j] = *(const float4*)(p + lane * 4 + j * 256);
  float rs;
  if (FIRST) {
    float s = 0.f;
#pragma unroll
    for (int j = 0; j < 4; j++)
      s += v[j].x * v[j].x + v[j].y * v[j].y + v[j].z * v[j].z + v[j].w * v[j].w;
    s = wsum(s);
    rs = rsqrtf(s * (1.0f / D) + 1e-6f);
    if (lane == 0) rinv[row] = rs;
  } else {
    rs = rinv[row];
  }
#pragma unroll
  for (int j = 0; j < 4; j++) {
    float4 w4 = *(const float4*)(cw + lane * 4 + j * 256);
    ushort4 o;
    o.x = f2b(v[j].x * rs * w4.x);
    o.y = f2b(v[j].y * rs * w4.y);
    o.z = f2b(v[j].z * rs * w4.z);
    o.w = f2b(v[j].w * rs * w4.w);
    *(ushort4*)&xb[(size_t)row * D + lane * 4 + j * 256] = o;
  }
}

// ---- transpose+convert the three projection weights -> WT[n][k] bf16 ----
__global__ void k_wtrans(const float* __restrict__ W0, const float* __restrict__ W1,
                         const float* __restrict__ W2, u16* __restrict__ WT) {
  __shared__ float tl[64][65];
  const float* W = blockIdx.z == 0 ? W0 : blockIdx.z == 1 ? W1 : W2;
  u16* dst = WT + (size_t)blockIdx.z * D * D;
  int bx = blockIdx.x, by = blockIdx.y;
  int t = threadIdx.x;
  int r = t >> 6, c = t & 63;
#pragma unroll
  for (int i = 0; i < 64; i += 4)
    tl[i + r][c] = W[(size_t)(bx * 64 + i + r) * D + by * 64 + c];
  __syncthreads();
#pragma unroll
  for (int i = 0; i < 64; i += 4)
    dst[(size_t)(by * 64 + i + r) * D + bx * 64 + c] = f2b(tl[c][i + r]);
}

// ---- pack [aw|tw] -> atw[n=32][k=1024] bf16 ----
__global__ void k_atw(const float* __restrict__ aw, const float* __restrict__ tw,
                      u16* __restrict__ atw) {
  int idx = blockIdx.x * 256 + threadIdx.x;  // 32768
  int n = idx >> 10, k = idx & 1023;
  float v = (n < 16) ? aw[(size_t)k * 16 + n] : tw[(size_t)k * 16 + (n - 16)];
  atw[idx] = f2b(v);
}

// ---- MFMA projection GEMM: xb(16384x1024 bf16) @ W (via WT[n][k] bf16) ----
// 1D grid 1024, XCD-chunked swizzle (T1): block bid -> XCD bid%8; swz gives
// each XCD 16 consecutive m-blocks x all 8 n-blocks, so its 8 B-panels
// (2 MB) stay L2-resident. Bijective (1024 % 8 == 0).
template <bool NORM>
__global__ __launch_bounds__(256) void k_proj_mfma(
    const u16* __restrict__ xb, const u16* __restrict__ WT,
    const float* __restrict__ hw, u16* __restrict__ outp) {
  __shared__ u16 As[128 * 32];
  __shared__ u16 Bs[128 * 32];
  int t = threadIdx.x;
  int wave = t >> 6, lane = t & 63;
  int wm = wave >> 1, wn = wave & 1;
  int bid = blockIdx.x;
  int swz = (bid & 7) * 128 + (bid >> 3);
  int mb = swz >> 3, nb = swz & 7;
  int m0 = mb * 128, n0 = nb * 128;
  int quad = lane >> 4, l15 = lane & 15;
  int rl = lane >> 2;
  int q  = (lane & 3) ^ swz4(rl);

  f32x4 acc[4][4] = {};

  int aoff[4], boff[4];
#pragma unroll
  for (int f = 0; f < 4; f++) {
    aoff[f] = (wm * 64 + f * 16 + l15) * 32 + (quad ^ swz4(l15)) * 8;
    boff[f] = (wn * 64 + f * 16 + l15) * 32 + (quad ^ swz4(l15)) * 8;
  }
  const u16* ga0 = xb + (size_t)(m0 + wave * 32 + rl) * D + q * 8;
  const u16* ga1 = ga0 + 16 * D;
  const u16* gb0 = WT + (size_t)(n0 + wave * 32 + rl) * D + q * 8;
  const u16* gb1 = gb0 + 16 * D;
  u16* lA0 = &As[(wave * 32) * 32];
  u16* lA1 = &As[(wave * 32 + 16) * 32];
  u16* lB0 = &Bs[(wave * 32) * 32];
  u16* lB1 = &Bs[(wave * 32 + 16) * 32];

  for (int k0 = 0; k0 < D; k0 += 32) {
    dma16(ga0 + k0, lA0);
    dma16(ga1 + k0, lA1);
    dma16(gb0 + k0, lB0);
    dma16(gb1 + k0, lB1);
    __syncthreads();
    bf16x8 af[4], bfr[4];
#pragma unroll
    for (int f = 0; f < 4; f++) {
      af[f]  = *(const bf16x8*)&As[aoff[f]];
      bfr[f] = *(const bf16x8*)&Bs[boff[f]];
    }
#pragma unroll
    for (int i = 0; i < 4; i++)
#pragma unroll
      for (int j = 0; j < 4; j++)
        acc[i][j] = __builtin_amdgcn_mfma_f32_16x16x32_bf16(af[i], bfr[j], acc[i][j], 0, 0, 0);
    __syncthreads();
  }

  int h = nb * 2 + wn;
  float hwv[4];
  if (NORM) {
#pragma unroll
    for (int f = 0; f < 4; f++) hwv[f] = hw[f * 16 + l15];
  }
#pragma unroll
  for (int fm = 0; fm < 4; fm++) {
    f32x4 rn = {};
    if (NORM) {
      f32x4 ss = acc[fm][0] * acc[fm][0] + acc[fm][1] * acc[fm][1] +
                 acc[fm][2] * acc[fm][2] + acc[fm][3] * acc[fm][3];
#pragma unroll
      for (int c = 0; c < 4; c++) {
        float s = rsum16(ss[c]);
        rn[c] = rsqrtf(s * (1.f / 64) + 1e-6f);
      }
    }
#pragma unroll
    for (int r = 0; r < 4; r++) {
      int gr = m0 + wm * 64 + fm * 16 + quad * 4 + r;
      int b = gr >> 11, s_ = gr & 2047;
      size_t base = ((size_t)(b * 16 + h) * S + s_) * 64 + l15;
#pragma unroll
      for (int fn = 0; fn < 4; fn++) {
        float v = acc[fm][fn][r];
        if (NORM) v *= rn[r] * hwv[fn];
        outp[base + fn * 16] = f2b(v);
      }
    }
  }
}

// ---- alpha/theta via MFMA: sigmoid(xs @ atw^T + bias), theta *= MAX_LR ----
__global__ __launch_bounds__(256) void k_ate2(
    const u16* __restrict__ xb, const u16* __restrict__ atw,
    const float* __restrict__ ab, const float* __restrict__ tb,
    float* __restrict__ alpha, float* __restrict__ theta) {
  __shared__ u16 As[2][128 * 32];
  __shared__ u16 Bs[2][32 * 32];
  int t = threadIdx.x;
  int wave = t >> 6, lane = t & 63;
  int m0 = blockIdx.x * 128;
  int quad = lane >> 4, l15 = lane & 15;
  int rl = lane >> 2;
  int q = (lane & 3) ^ swz4(rl);

  f32x4 acc[2][2] = {};
  int aoff[2], boff[2];
#pragma unroll
  for (int f = 0; f < 2; f++) {
    aoff[f] = (wave * 32 + f * 16 + l15) * 32 + (quad ^ swz4(l15)) * 8;
    boff[f] = (f * 16 + l15) * 32 + (quad ^ swz4(l15)) * 8;
  }
  const u16* ga0 = xb + (size_t)(m0 + wave * 32 + rl) * D + q * 8;
  const u16* ga1 = ga0 + 16 * D;
  const u16* gb = atw + (size_t)((wave & 1) * 16 + rl) * D + (wave >> 1) * 32 + q * 8;
  u16* lA0h0 = &As[0][(wave * 32) * 32];
  u16* lA1h0 = &As[0][(wave * 32 + 16) * 32];
  u16* lA0h1 = &As[1][(wave * 32) * 32];
  u16* lA1h1 = &As[1][(wave * 32 + 16) * 32];
  u16* lB    = &Bs[wave >> 1][((wave & 1) * 16) * 32];

  for (int k0 = 0; k0 < D; k0 += 64) {
    dma16(ga0 + k0, lA0h0);
    dma16(ga1 + k0, lA1h0);
    dma16(ga0 + k0 + 32, lA0h1);
    dma16(ga1 + k0 + 32, lA1h1);
    dma16(gb + k0, lB);
    __syncthreads();
#pragma unroll
    for (int h = 0; h < 2; h++) {
      bf16x8 af[2], bfr[2];
#pragma unroll
      for (int f = 0; f < 2; f++) {
        af[f]  = *(const bf16x8*)&As[h][aoff[f]];
        bfr[f] = *(const bf16x8*)&Bs[h][boff[f]];
      }
#pragma unroll
      for (int i = 0; i < 2; i++)
#pragma unroll
        for (int j = 0; j < 2; j++)
          acc[i][j] = __builtin_amdgcn_mfma_f32_16x16x32_bf16(af[i], bfr[j], acc[i][j], 0, 0, 0);
    }
    __syncthreads();
  }

#pragma unroll
  for (int fn = 0; fn < 2; fn++) {
    float bias = (fn == 0) ? ab[l15] : tb[l15];
    float scale = (fn == 0) ? 1.f : 0.01f;  // MAX_LR
    float* dst = (fn == 0) ? alpha : theta;
#pragma unroll
    for (int fm = 0; fm < 2; fm++) {
#pragma unroll
      for (int r = 0; r < 4; r++) {
        int gr = m0 + wave * 32 + fm * 16 + quad * 4 + r;
        int b = gr >> 11, s_ = gr & 2047;
        float v = sigmoidf(acc[fm][fn][r] + bias) * scale;
        dst[(long)(b * 16 + l15) * S + s_] = v;
      }
    }
  }
}

// ---------------- per-bh mean of alpha ----------------
__global__ void k_mean(const float* __restrict__ alpha, float* __restrict__ amean) {
  int bh = blockIdx.x, t = threadIdx.x;
  float sa = 0.f;
  for (int i = t; i < S; i += 256) sa += alpha[(long)bh * S + i];
  sa = wsum(sa);
  __shared__ float sh[4];
  int w = t >> 6, lane = t & 63;
  if (lane == 0) sh[w] = sa;
  __syncthreads();
  if (t == 0) amean[bh] = (sh[0] + sh[1] + sh[2] + sh[3]) * (1.f / S);
}

// ---- small-weight prep: W0T[i][k], W1b[i][o] (direct), W1T[o][i] bf16 ----
__global__ void k_wsmall(const float* __restrict__ W0, const float* __restrict__ W1,
                         u16* __restrict__ W0T, u16* __restrict__ W1b, u16* __restrict__ W1T) {
  int idx = blockIdx.x * 256 + threadIdx.x;  // 16384
  int sec = blockIdx.y;
  if (sec == 0) {
    int k = idx & 63, i = idx >> 6;
    W0T[idx] = f2b(W0[k * 256 + i]);
  } else if (sec == 1) {
    W1b[idx] = f2b(W1[idx]);
  } else {
    int i = idx & 255, o = idx >> 8;
    W1T[idx] = f2b(W1[i * 64 + o]);
  }
}

// ---- rows (row-major [s][64]) -> blocked-T tiles (all NR rows) ----
__global__ void k_keysT(const u16* __restrict__ keysg, u16* __restrict__ blk) {
  long idx = (long)blockIdx.x * 256 + threadIdx.x;  // NR*16
  int col = (int)(idx & 63);
  long s = (idx >> 6) * 4;
  ushort4 o;
  o.x = keysg[(size_t)s * 64 + col];
  o.y = keysg[(size_t)(s + 1) * 64 + col];
  o.z = keysg[(size_t)(s + 2) * 64 + col];
  o.w = keysg[(size_t)(s + 3) * 64 + col];
  *(ushort4*)&blk[((size_t)(s >> 4) * 4 + (col >> 4)) * 256 + (col & 15) * 16 + (s & 15)] = o;
}

// ==================== fused memory-grad kernel (round-3 proven) ====
// One block = 128 rows of one bh. Full chain: PRE -> gelu/gelu' -> h1 ->
// rmsnorm-bwd -> dh -> g1 (atomic) -> dh0 -> g0 (atomic).
// LDS 112 KB: S1(64K) ACTblk -> dh0blk ; S2(32K) W0sL -> dhR+dhblk ;
// S3(16K) keysblk (persistent).
__global__ __launch_bounds__(512, 2) void kfuse(
    const u16* __restrict__ keysv, const u16* __restrict__ vals,
    const u16* __restrict__ keysTb,
    const u16* __restrict__ W0T, const u16* __restrict__ W1T,
    const u16* __restrict__ W1b, const float* __restrict__ theta,
    float* __restrict__ g0t, float* __restrict__ g1t) {
  __shared__ u16 L[57344];
  u16* S1   = L;               // 32768 u16 (64 KB)
  u16* W0sL = L + 32768;       // 16384 u16 (32 KB), later dhR(8192)+dhblk(8192)
  u16* dhR  = L + 32768;
  u16* dhblk = L + 40960;
  u16* Kblk = L + 49152;       // 8192 u16 (16 KB)

  int t = threadIdx.x;
  int w = t >> 6, lane = t & 63;
  int quad = lane >> 4, l15 = lane & 15;
  int bh = blockIdx.y, strip = blockIdx.x;
  long grow = (long)bh * S + strip * 128;  // global row base
  int bswz = (quad ^ swz4(l15)) * 8;

  // ---- ph1: stage keysblk (dma16) + W0sL (reg-staged, chunk-swizzled) ----
  {
    const u16* ksrc = keysTb + (grow >> 4) * 1024 + (size_t)w * 1024 + lane * 8;
    dma16(ksrc, Kblk + w * 1024);
    dma16(ksrc + 512, Kblk + w * 1024 + 512);
    int i = t >> 1, c = t & 1;
    int key = swz4(i & 15);
    const u16* gsrc = W0T + i * 64 + c * 32;
    u16* ldst = W0sL + c * 8192 + i * 32;
#pragma unroll
    for (int j = 0; j < 4; j++)
      *(bf16x8*)&ldst[j * 8] = *(const bf16x8*)&gsrc[(j ^ key) * 8];
  }
  __syncthreads();

  // ---- ph2: PRE = keys @ W0  (M=16/wave, N=256, K=64) ----
  f32x4 acc2[4];   // reused for h1 later
  ushort4 gpr[16]; // gelu' in registers
  {
    f32x4 acc[16] = {};
    bf16x8 afA[2];
#pragma unroll
    for (int kc = 0; kc < 2; kc++) {
      union { bf16x8 v; u16 e[8]; } u;
#pragma unroll
      for (int j = 0; j < 8; j++) {
        int k = kc * 32 + quad * 8 + j;
        u.e[j] = Kblk[(w * 4 + (k >> 4)) * 256 + (k & 15) * 16 + l15];
      }
      afA[kc] = u.v;
    }
#pragma unroll
    for (int f = 0; f < 16; f++) {
      bf16x8 b0 = *(const bf16x8*)&W0sL[(f * 16 + l15) * 32 + bswz];
      bf16x8 b1 = *(const bf16x8*)&W0sL[8192 + (f * 16 + l15) * 32 + bswz];
      acc[f] = __builtin_amdgcn_mfma_f32_16x16x32_bf16(afA[0], b0, acc[f], 0, 0, 0);
      acc[f] = __builtin_amdgcn_mfma_f32_16x16x32_bf16(afA[1], b1, acc[f], 0, 0, 0);
    }
    __syncthreads();  // all W0sL reads done before anyone writes dhR (same region)

    // epi: act -> S1 blocked, gelu' -> registers
#pragma unroll
    for (int f = 0; f < 16; f++) {
      ushort4 oa, og;
#pragma unroll
      for (int r = 0; r < 4; r++) {
        float v = acc[f][r];
        float cdf = 0.5f * (1.0f + erff(v * 0.70710678118654752440f));
        float pdf = expf(-0.5f * v * v) * 0.3989422804014327f;
        ((u16*)&oa)[r] = f2b(v * cdf);
        ((u16*)&og)[r] = f2b(cdf + v * pdf);
      }
      *(ushort4*)&S1[(w * 16 + f) * 256 + l15 * 16 + quad * 4] = oa;
      gpr[f] = og;
    }
  }

  // ---- ph3: h1 = act @ W1 (M=16/wave, N=64, K=256); B-frags from global ----
  {
#pragma unroll
    for (int fn = 0; fn < 4; fn++) acc2[fn] = (f32x4){};
#pragma unroll
    for (int kc = 0; kc < 8; kc++) {
      union { bf16x8 v; u16 e[8]; } u;
#pragma unroll
      for (int j = 0; j < 8; j++) {
        int c = kc * 32 + quad * 8 + j;
        u.e[j] = S1[(w * 16 + (c >> 4)) * 256 + (c & 15) * 16 + l15];
      }
#pragma unroll
      for (int fn = 0; fn < 4; fn++) {
        bf16x8 bv = *(const bf16x8*)&W1T[(size_t)(fn * 16 + l15) * 256 + kc * 32 + quad * 8];
        acc2[fn] = __builtin_amdgcn_mfma_f32_16x16x32_bf16(u.v, bv, acc2[fn], 0, 0, 0);
      }
    }
  }

  // ---- ph3-epi: pf-rmsnorm bwd -> dh (dhR chunk-swz + dhblk blocked) ----
  {
    f32x4 ss = acc2[0] * acc2[0] + acc2[1] * acc2[1] +
               acc2[2] * acc2[2] + acc2[3] * acc2[3];
    f32x4 rrms, th2;
    long rowg0 = grow + w * 16 + quad * 4;
#pragma unroll
    for (int r = 0; r < 4; r++) {
      float s = rsum16(ss[r]);
      rrms[r] = rsqrtf(s * (1.f / 64) + 1e-8f);
      th2[r] = 2.f * theta[rowg0 + r];
    }
    f32x4 hn[4], dp[4];
    f32x4 dyp = {};
#pragma unroll
    for (int fn = 0; fn < 4; fn++) {
      int col = fn * 16 + l15;
#pragma unroll
      for (int r = 0; r < 4; r++) {
        float h = acc2[fn][r] * rrms[r];
        float k = b2f(keysv[(rowg0 + r) * 64 + col]);
        float v = b2f(vals[(rowg0 + r) * 64 + col]);
        float d = th2[r] * (h + k - v);
        hn[fn][r] = h;
        dp[fn][r] = d;
        dyp[r] += d * h;
      }
    }
#pragma unroll
    for (int r = 0; r < 4; r++) dyp[r] = rsum16(dyp[r]);
#pragma unroll
    for (int fn = 0; fn < 4; fn++) {
      int col = fn * 16 + l15;
      ushort4 ob;
#pragma unroll
      for (int r = 0; r < 4; r++) {
        float d = (dp[fn][r] - hn[fn][r] * dyp[r] * (1.f / 64)) * rrms[r];
        u16 db = f2b(d);
        ((u16*)&ob)[r] = db;
        int row = w * 16 + quad * 4 + r;
        int g = ((col >> 3) & 3) ^ swz4(row & 15);
        dhR[(col >> 5) * 4096 + row * 32 + g * 8 + (col & 7)] = db;
      }
      *(ushort4*)&dhblk[(w * 4 + fn) * 256 + l15 * 16 + quad * 4] = ob;
    }
  }
  __syncthreads();  // dh + ACT fully visible

  // ---- ph4: g1[o][i] += dh^T @ act  (kg pattern, K=128 rows) ----
  {
    int qh = quad >> 1, ql = (quad & 1) * 8;
    f32x4 a3[4][2] = {};
#pragma unroll
    for (int ks = 0; ks < 4; ks++) {
      int s16 = ks * 2 + qh;
      bf16x8 af[4], bf2[2];
#pragma unroll
      for (int m = 0; m < 4; m++)
        af[m] = *(const bf16x8*)&dhblk[(s16 * 4 + m) * 256 + l15 * 16 + ql];
#pragma unroll
      for (int f2 = 0; f2 < 2; f2++)
        bf2[f2] = *(const bf16x8*)&S1[(s16 * 16 + w * 2 + f2) * 256 + l15 * 16 + ql];
#pragma unroll
      for (int m = 0; m < 4; m++)
#pragma unroll
        for (int f2 = 0; f2 < 2; f2++)
          a3[m][f2] = __builtin_amdgcn_mfma_f32_16x16x32_bf16(af[m], bf2[f2], a3[m][f2], 0, 0, 0);
    }
    float* gp1 = g1t + (size_t)bh * 16384;
#pragma unroll
    for (int m = 0; m < 4; m++)
#pragma unroll
      for (int f2 = 0; f2 < 2; f2++) {
        int n = w * 32 + f2 * 16 + l15;
#pragma unroll
        for (int r = 0; r < 4; r++)
          atomicAdd(&gp1[(size_t)(m * 16 + quad * 4 + r) * 256 + n], a3[m][f2][r]);
      }
  }
  __syncthreads();  // ACT dead; S1 reusable for dh0blk

  // ---- ph5: dh0 = (dh @ W1^T) .* gelu'  -> S1 blocked ----
  {
    f32x4 a5[16] = {};
    bf16x8 afd[2];
#pragma unroll
    for (int kc = 0; kc < 2; kc++)
      afd[kc] = *(const bf16x8*)&dhR[kc * 4096 + (w * 16 + l15) * 32 + bswz];
#pragma unroll
    for (int f = 0; f < 16; f++) {
#pragma unroll
      for (int kc = 0; kc < 2; kc++) {
        bf16x8 bv = *(const bf16x8*)&W1b[(size_t)(f * 16 + l15) * 64 + kc * 32 + quad * 8];
        a5[f] = __builtin_amdgcn_mfma_f32_16x16x32_bf16(afd[kc], bv, a5[f], 0, 0, 0);
      }
    }
#pragma unroll
    for (int f = 0; f < 16; f++) {
      ushort4 od;
#pragma unroll
      for (int r = 0; r < 4; r++)
        ((u16*)&od)[r] = f2b(a5[f][r] * b2f(((u16*)&gpr[f])[r]));
      *(ushort4*)&S1[(w * 16 + f) * 256 + l15 * 16 + quad * 4] = od;
    }
  }
  __syncthreads();

  // ---- ph6: g0[k][i] += keys^T @ dh0  (kg pattern) ----
  {
    int qh = quad >> 1, ql = (quad & 1) * 8;
    f32x4 a6[4][2] = {};
#pragma unroll
    for (int ks = 0; ks < 4; ks++) {
      int s16 = ks * 2 + qh;
      bf16x8 af[4], bf2[2];
#pragma unroll
      for (int m = 0; m < 4; m++)
        af[m] = *(const bf16x8*)&Kblk[(s16 * 4 + m) * 256 + l15 * 16 + ql];
#pragma unroll
      for (int f2 = 0; f2 < 2; f2++)
        bf2[f2] = *(const bf16x8*)&S1[(s16 * 16 + w * 2 + f2) * 256 + l15 * 16 + ql];
#pragma unroll
      for (int m = 0; m < 4; m++)
#pragma unroll
        for (int f2 = 0; f2 < 2; f2++)
          a6[m][f2] = __builtin_amdgcn_mfma_f32_16x16x32_bf16(af[m], bf2[f2], a6[m][f2], 0, 0, 0);
    }
    float* gp0 = g0t + (size_t)bh * 16384;
#pragma unroll
    for (int m = 0; m < 4; m++)
#pragma unroll
      for (int f2 = 0; f2 < 2; f2++) {
        int n = w * 32 + f2 * 16 + l15;
#pragma unroll
        for (int r = 0; r < 4; r++)
          atomicAdd(&gp0[(size_t)(m * 16 + quad * 4 + r) * 256 + n], a6[m][f2][r]);
      }
  }
}

// ==================== fused retrieve kernel (64 KB LDS, direct-global) ====
// One block = 128 rows (one strip) of one bh. q(row-major) @ nW0 -> gelu ->
// act(LDS) @ nW1 -> nan0 + pf-rmsnorm + q-residual -> out. A/B fragments
// read direct from global; LDS = act only; zero barriers.
__global__ __launch_bounds__(512, 2) void kret(
    const u16* __restrict__ qp, const u16* __restrict__ nW0T,
    const u16* __restrict__ nW1T, float* __restrict__ outp) {
  __shared__ u16 S1[32768];  // 64 KB act blocked

  int t = threadIdx.x;
  int w = t >> 6, lane = t & 63;
  int quad = lane >> 4, l15 = lane & 15;
  int bh = blockIdx.y, strip = blockIdx.x;
  long grow = (long)bh * S + strip * 128;

  // ---- ph2: PRE = q @ nW0 (M=16/wave, N=256, K=64); act=gelu -> S1 ----
  {
    f32x4 acc[16] = {};
    const u16* qrow = qp + (grow + w * 16 + l15) * 64 + quad * 8;
    bf16x8 afA0 = *(const bf16x8*)(qrow);
    bf16x8 afA1 = *(const bf16x8*)(qrow + 32);
    const u16* W0p = nW0T + (size_t)bh * 16384;
#pragma unroll
    for (int f = 0; f < 16; f++) {
      bf16x8 b0 = *(const bf16x8*)&W0p[(f * 16 + l15) * 64 + quad * 8];
      bf16x8 b1 = *(const bf16x8*)&W0p[(f * 16 + l15) * 64 + 32 + quad * 8];
      acc[f] = __builtin_amdgcn_mfma_f32_16x16x32_bf16(afA0, b0, acc[f], 0, 0, 0);
      acc[f] = __builtin_amdgcn_mfma_f32_16x16x32_bf16(afA1, b1, acc[f], 0, 0, 0);
    }
#pragma unroll
    for (int f = 0; f < 16; f++) {
      ushort4 oa;
#pragma unroll
      for (int r = 0; r < 4; r++) ((u16*)&oa)[r] = f2b(geluf(acc[f][r]));
      *(ushort4*)&S1[(w * 16 + f) * 256 + l15 * 16 + quad * 4] = oa;
    }
  }
  // ph3 reads only own-wave S1 rows — no barrier.

  // ---- ph3: h1 = act @ nW1 (M=16/wave, N=64, K=256) ----
  f32x4 acc2[4];
#pragma unroll
  for (int fn = 0; fn < 4; fn++) acc2[fn] = (f32x4){};
  const u16* W1p = nW1T + (size_t)bh * 16384;
#pragma unroll
  for (int kc = 0; kc < 8; kc++) {
    union { bf16x8 v; u16 e[8]; } u;
#pragma unroll
    for (int j = 0; j < 8; j++) {
      int c = kc * 32 + quad * 8 + j;
      u.e[j] = S1[(w * 16 + (c >> 4)) * 256 + (c & 15) * 16 + l15];
    }
#pragma unroll
    for (int fn = 0; fn < 4; fn++) {
      bf16x8 bv = *(const bf16x8*)&W1p[(size_t)(fn * 16 + l15) * 256 + kc * 32 + quad * 8];
      acc2[fn] = __builtin_amdgcn_mfma_f32_16x16x32_bf16(u.v, bv, acc2[fn], 0, 0, 0);
    }
  }

  // ---- epilogue: nan0 + pf_rmsnorm + q residual -> out (merge heads) ----
  {
    f32x4 hv[4];
    f32x4 ss = {};
#pragma unroll
    for (int fn = 0; fn < 4; fn++) {
#pragma unroll
      for (int r = 0; r < 4; r++) {
        float v = nan0(acc2[fn][r]);
        hv[fn][r] = v;
        ss[r] += v * v;
      }
    }
    f32x4 rrms;
#pragma unroll
    for (int r = 0; r < 4; r++) {
      float s = rsum16(ss[r]);
      rrms[r] = rsqrtf(s * (1.f / 64) + 1e-8f);
    }
    long b = bh >> 4, hh = bh & 15;
#pragma unroll
    for (int r = 0; r < 4; r++) {
      long s_ = strip * 128 + w * 16 + quad * 4 + r;
      long gr = grow + w * 16 + quad * 4 + r;
      size_t obase = (size_t)(b * S + s_) * D + hh * 64;
#pragma unroll
      for (int fn = 0; fn < 4; fn++) {
        int col = fn * 16 + l15;
        outp[obase + col] = hv[fn][r] * rrms[r] + b2f(qp[gr * 64 + col]);
      }
    }
  }
}

// ---------------- zero-fill ----------------
__global__ void k_zero(float* __restrict__ p, long n) {
  long i = (long)blockIdx.x * 256 + threadIdx.x;
  if (i < n) p[i] = 0.f;
}

// ---------------- grad-norm clip coefficient per bh ----------------
__global__ void k_clip(const float* __restrict__ g0, const float* __restrict__ g1,
                       float* __restrict__ coef) {
  int bh = blockIdx.x, t = threadIdx.x;
  const float* p0 = g0 + (long)bh * 16384;
  const float* p1 = g1 + (long)bh * 16384;
  float s = 0.f;
  for (int i = t; i < 16384; i += 256) {
    float a = p0[i]; s += a * a;
    float b = p1[i]; s += b * b;
  }
  s = wsum(s);
  __shared__ float sh[4];
  int w = t >> 6, lane = t & 63;
  if (lane == 0) sh[w] = s;
  __syncthreads();
  if (t == 0) {
    float tot = sh[0] + sh[1] + sh[2] + sh[3];
    float c = 10.f / (sqrtf(tot) + 1e-6f);
    coef[bh] = fminf(c, 1.f);
  }
}

// ---- weight update -> transposed bf16 fast weights for retrieve MFMA ----
__global__ void k_updT(const float* __restrict__ W0, const float* __restrict__ W1,
                       const float* __restrict__ g0t, const float* __restrict__ g1t,
                       const float* __restrict__ amean, const float* __restrict__ coef,
                       u16* __restrict__ nW0T, u16* __restrict__ nW1T) {
  long i = (long)blockIdx.x * 256 + threadIdx.x;  // 2 * BH * 16384
  int half = (int)(i >> 21);
  long j = i & ((1L << 21) - 1);
  int bh = (int)(j >> 14);
  int idx = (int)(j & 16383);
  float a = 1.f - amean[bh], cf = coef[bh];
  if (half == 0) {
    int k = idx & 63, ii = idx >> 6;
    float w = W0[k * 256 + ii];
    float nw = a * w - cf * g0t[(long)bh * 16384 + k * 256 + ii];
    if (!finitef(nw)) nw = w;
    nW0T[j] = f2b(nw);
  } else {
    int ii = idx & 255, o = idx >> 8;
    float w = W1[ii * 64 + o];
    float nw = a * w - cf * g1t[(long)bh * 16384 + idx];
    if (!finitef(nw)) nw = w;
    nW1T[j] = f2b(nw);
  }
}

extern "C" void kernel_launch(void* const* d_in, const int* in_sizes, int n_in,
                              void* d_out, int out_size, void* d_ws, size_t ws_size,
                              hipStream_t stream) {
  const float* x   = (const float*)d_in[0];
  const float* W_K = (const float*)d_in[1];
  const float* W_V = (const float*)d_in[2];
  const float* W_Q = (const float*)d_in[3];
  const float* mW0 = (const float*)d_in[4];
  const float* mW1 = (const float*)d_in[5];
  const float* knw = (const float*)d_in[6];
  const float* qnw = (const float*)d_in[7];
  const float* snw = (const float*)d_in[8];
  const float* rnw = (const float*)d_in[9];
  const float* aw  = (const float*)d_in[10];
  const float* ab  = (const float*)d_in[11];
  const float* tw  = (const float*)d_in[12];
  const float* tb  = (const float*)d_in[13];
  float* out = (float*)d_out;
  (void)ws_size; (void)in_sizes; (void)n_in; (void)out_size;

  // workspace carve-up
  char* w = (char*)d_ws;
  auto alloc = [&](size_t bytes) {
    char* p = w;
    w += (bytes + 255) / 256 * 256;
    return p;
  };
  float* rinv   = (float*)alloc((size_t)BS * 4);
  u16*   xs     = (u16*)alloc((size_t)BS * D * 2);        // 32 MB
  u16*   WTb    = (u16*)alloc((size_t)3 * D * D * 2);     // 6 MB
  u16*   keys   = (u16*)alloc(NR * 64 * 2);               // 32 MB (reused as q)
  u16*   vals   = (u16*)alloc(NR * 64 * 2);               // 32 MB
  float* alpha  = (float*)alloc(NR * 4);                  // 1 MB
  float* theta  = (float*)alloc(NR * 4);                  // 1 MB
  float* amean  = (float*)alloc(BH * 4);
  float* coef   = (float*)alloc(BH * 4);
  u16*   W0T    = (u16*)alloc(16384 * 2);
  u16*   W1b    = (u16*)alloc(16384 * 2);
  u16*   W1T    = (u16*)alloc(16384 * 2);
  u16*   atw    = (u16*)alloc((size_t)32 * D * 2);        // 64 KB
  u16*   keysTb = (u16*)alloc(NR * 64 * 2);               // 32 MB (blocked)
  float* g0t    = (float*)alloc((size_t)BH * 16384 * 4);  // 8 MB
  float* g1t    = (float*)alloc((size_t)BH * 16384 * 4);  // 8 MB
  u16*   nW0T   = (u16*)alloc((size_t)BH * 16384 * 2);    // 4 MB
  u16*   nW1T   = (u16*)alloc((size_t)BH * 16384 * 2);    // 4 MB

  // ---- store path ----
  k_xnorm<true><<<BS / 4, 256, 0, stream>>>(x, snw, rinv, xs);
  k_wtrans<<<dim3(16, 16, 3), 256, 0, stream>>>(W_K, W_V, W_Q, WTb);
  k_atw<<<128, 256, 0, stream>>>(aw, tw, atw);
  k_proj_mfma<true><<<1024, 256, 0, stream>>>(xs, WTb, knw, keys);
  k_proj_mfma<false><<<1024, 256, 0, stream>>>(xs, WTb + (size_t)D * D, nullptr, vals);
  k_ate2<<<BS / 128, 256, 0, stream>>>(xs, atw, ab, tb, alpha, theta);
  k_mean<<<BH, 256, 0, stream>>>(alpha, amean);
  k_wsmall<<<dim3(64, 3), 256, 0, stream>>>(mW0, mW1, W0T, W1b, W1T);
  k_zero<<<(int)((2L * BH * 16384 + 255) / 256), 256, 0, stream>>>(g0t, 2L * BH * 16384);

  // ---- memory grad: blocked keys once, then one fused kernel ----
  k_keysT<<<(int)(NR / 16), 256, 0, stream>>>(keys, keysTb);
  kfuse<<<dim3(16, BH), 512, 0, stream>>>(keys, vals, keysTb, W0T, W1T, W1b,
                                          theta, g0t, g1t);

  k_clip<<<BH, 256, 0, stream>>>(g0t, g1t, coef);
  k_updT<<<(int)(2L * BH * 16384 / 256), 256, 0, stream>>>(
      mW0, mW1, g0t, g1t, amean, coef, nW0T, nW1T);

  // ---- retrieve: q proj, one fused kernel (q read row-major; no qTb) ----
  k_xnorm<false><<<BS / 4, 256, 0, stream>>>(x, rnw, rinv, xs);
  u16* q = keys;
  k_proj_mfma<true><<<1024, 256, 0, stream>>>(xs, WTb + (size_t)2 * D * D, qnw, q);
  kret<<<dim3(16, BH), 512, 0, stream>>>(q, nW0T, nW1T, out);
}